// Round 10
// baseline (307.343 us; speedup 1.0000x reference)
//
#include <hip/hip_runtime.h>
#include <hip/hip_fp16.h>
#include <math.h>

#define LRELU_SLOPE 0.2f
#define MAXD 128
#define SCAN_VPB 2048

typedef unsigned short u16;
struct __align__(8) bh4 { u16 x, y, z, w; };
struct __align__(16) bh8 { u16 v[8]; };
typedef __attribute__((ext_vector_type(8))) short s8v;       // 16B copy unit
typedef __attribute__((ext_vector_type(8))) _Float16 h8v;    // MFMA f16 operand
typedef __attribute__((ext_vector_type(4))) float f4v;       // MFMA acc

__device__ __forceinline__ u16 f2h(float f){
  _Float16 h = (_Float16)f;
  return *(u16*)&h;
}
__device__ __forceinline__ float h2f(u16 u){
  _Float16 h = *(_Float16*)&u;
  return (float)h;
}
__device__ __forceinline__ float hlo(unsigned u){ return h2f((u16)(u & 0xFFFFu)); }
__device__ __forceinline__ float hhi(unsigned u){ return h2f((u16)(u >> 16)); }

__device__ __forceinline__ float wave_reduce_max(float v){
  #pragma unroll
  for (int off = 32; off; off >>= 1) v = fmaxf(v, __shfl_xor(v, off, 64));
  return v;
}
__device__ __forceinline__ float wave_reduce_sum(float v){
  #pragma unroll
  for (int off = 32; off; off >>= 1) v += __shfl_xor(v, off, 64);
  return v;
}
__device__ __forceinline__ float red16_sum(float v){
  #pragma unroll
  for (int off = 1; off < 16; off <<= 1) v += __shfl_xor(v, off, 64);
  return v;
}

// ---------------- front: weight fp16 transpose + attn projections + count + goff ----------------
// prep layout: [0..53] proj(f*9+j), [54..81] as1p(h*7+c), [82..109] ad1p(h*7+c)
__global__ __launch_bounds__(256) void k_front(
    const float* __restrict__ W2, const float* __restrict__ W3,
    u16* __restrict__ Wt2, u16* __restrict__ Wt3,
    const float* __restrict__ W1, const float* __restrict__ as1, const float* __restrict__ ad1,
    const float* __restrict__ We1, const float* __restrict__ ae1,
    const float* __restrict__ We2, const float* __restrict__ ae2,
    const float* __restrict__ We3, const float* __restrict__ ae3,
    float* __restrict__ prep,
    const int* __restrict__ dst, int E, int* __restrict__ indeg,
    const int* __restrict__ batch, int n, int G, int* __restrict__ goff){
  int b = blockIdx.x, k = threadIdx.x;
  if (b < 256){
    Wt2[(size_t)b * 256 + k] = f2h(W2[(size_t)k * 256 + b]);
  } else if (b < 320){
    int c = b - 256;
    Wt3[(size_t)c * 256 + k] = f2h(W3[(size_t)k * 64 + c]);
  } else if (b == 320){
    int wv = k >> 6, l = k & 63;
    for (int task = wv; task < 110; task += 4){
      float v;
      if (task < 54){
        int f = task / 9, j = task % 9;
        if (j < 4)      v = We1[f * 256 + j * 64 + l] * ae1[j * 64 + l];
        else if (j < 8) v = We2[f * 256 + (j - 4) * 64 + l] * ae2[(j - 4) * 64 + l];
        else            v = We3[f * 64 + l] * ae3[l];
      } else if (task < 82){
        int q = task - 54; int h = q / 7, c = q % 7;
        v = W1[c * 256 + h * 64 + l] * as1[h * 64 + l];
      } else {
        int q = task - 82; int h = q / 7, c = q % 7;
        v = W1[c * 256 + h * 64 + l] * ad1[h * 64 + l];
      }
      float s = wave_reduce_sum(v);
      if (l == 0) prep[task] = s;
    }
  } else {
    int e = (b - 321) * 256 + k;
    if (e < E) atomicAdd(&indeg[dst[e]], 1);
    if (e < n){
      int bb = batch[e];
      if (e == 0){
        for (int g = 0; g <= bb; ++g) goff[g] = 0;
      } else {
        int pb = batch[e - 1];
        for (int g = pb + 1; g <= bb; ++g) goff[g] = e;
      }
      if (e == n - 1){
        for (int g = bb + 1; g <= G; ++g) goff[g] = n;
      }
    }
  }
}
__global__ __launch_bounds__(256) void k_scan_local(const int* __restrict__ in, int* __restrict__ out,
                                                    int* __restrict__ bsum, int n, int add_k){
  __shared__ int ts[256];
  int b = blockIdx.x, t = threadIdx.x;
  int base = b * SCAN_VPB;
  int vals[8]; int s = 0;
  #pragma unroll
  for (int j = 0; j < 8; ++j){
    int idx = base + t * 8 + j;
    int v = (idx < n) ? (in[idx] + add_k) : 0;
    vals[j] = v; s += v;
  }
  ts[t] = s; __syncthreads();
  #pragma unroll
  for (int off = 1; off < 256; off <<= 1){
    int x = (t >= off) ? ts[t - off] : 0;
    __syncthreads();
    ts[t] += x;
    __syncthreads();
  }
  int excl = t ? ts[t - 1] : 0;
  #pragma unroll
  for (int j = 0; j < 8; ++j){
    excl += vals[j];
    int idx = base + t * 8 + j;
    if (idx < n) out[idx + 1] = excl;
  }
  if (b == 0 && t == 0) out[0] = 0;
  if (t == 255 && bsum) bsum[b] = ts[255];
}
// fused: each block computes its own prefix of bsum (B <= 64 entries) then adds
__global__ __launch_bounds__(256) void k_scan_add(int* __restrict__ out, const int* __restrict__ bsum, int n){
  int b = blockIdx.x, t = threadIdx.x;
  int add = 0;
  for (int j = 0; j < b; ++j) add += bsum[j];
  if (add == 0) return;
  int base = b * SCAN_VPB;
  #pragma unroll
  for (int j = 0; j < 8; ++j){
    int idx = base + t + j * 256;
    if (idx < n) out[idx + 1] += add;
  }
}
// scatter real edges + self-loops; separate src / eid arrays
__global__ void k_scatter(const int* __restrict__ src0, const int* __restrict__ dst0, int E, int n,
                          const int* __restrict__ row_off, int* __restrict__ cursor,
                          int* __restrict__ csr_src, int* __restrict__ csr_eid){
  int e = blockIdx.x * blockDim.x + threadIdx.x;
  if (e < E){
    int d = dst0[e];
    int pos = row_off[d] + atomicAdd(&cursor[d], 1);
    csr_src[pos] = src0[e];
    csr_eid[pos] = e;
  } else if (e < E + n){
    int i = e - E;
    int pos = row_off[i + 1] - 1;
    csr_src[pos] = i;
    csr_eid[pos] = E + i;
  }
}

// eterm in CSR order (coalesced writes; agg phase-1 reads coalesced) with inline loop-attr
// for self-loop slots; plus layer-1 sd + padded x for trailing threads.
__global__ void k_eterm_csr(const int* __restrict__ csr_eid, const int* __restrict__ row_off,
                            const float* __restrict__ ea,
                            const float* __restrict__ prep, const float* __restrict__ x,
                            float4* __restrict__ et1c, float4* __restrict__ et2c,
                            float* __restrict__ et3c,
                            float* __restrict__ sterm, float* __restrict__ dterm,
                            float* __restrict__ xp,
                            int E, int Ef, int n){
  int pos = blockIdx.x * blockDim.x + threadIdx.x;
  if (pos < Ef){
    int eid = csr_eid[pos];
    float la[6];
    const float* p;
    if (eid < E){
      p = ea + (size_t)eid * 6;
    } else {
      // self-loop: attr = mean of this node's incoming real-edge attrs
      int i = eid - E;
      int s0 = row_off[i], e0 = row_off[i + 1] - 1;
      #pragma unroll
      for (int f = 0; f < 6; ++f) la[f] = 0.f;
      for (int j = s0; j < e0; ++j){
        int e2 = csr_eid[j];
        const float* q = &ea[(size_t)e2 * 6];
        #pragma unroll
        for (int f = 0; f < 6; ++f) la[f] += q[f];
      }
      float inv = 1.0f / fmaxf((float)(e0 - s0), 1.0f);
      #pragma unroll
      for (int f = 0; f < 6; ++f) la[f] *= inv;
      p = la;
    }
    float acc[9] = {};
    #pragma unroll
    for (int f = 0; f < 6; ++f){
      float v = p[f];
      #pragma unroll
      for (int j = 0; j < 9; ++j) acc[j] += v * prep[f * 9 + j];
    }
    et1c[pos] = make_float4(acc[0], acc[1], acc[2], acc[3]);
    et2c[pos] = make_float4(acc[4], acc[5], acc[6], acc[7]);
    et3c[pos] = acc[8];
  } else if (pos < Ef + n){
    int i = pos - Ef;
    float xr[8];
    #pragma unroll
    for (int c = 0; c < 7; ++c) xr[c] = x[(size_t)i * 7 + c];
    xr[7] = 0.f;
    *(float4*)&xp[(size_t)i * 8] = make_float4(xr[0], xr[1], xr[2], xr[3]);
    *(float4*)&xp[(size_t)i * 8 + 4] = make_float4(xr[4], xr[5], xr[6], xr[7]);
    float4 sv, dv;
    float* sp = (float*)&sv; float* dp = (float*)&dv;
    #pragma unroll
    for (int h = 0; h < 4; ++h){
      float s = 0.f, d = 0.f;
      #pragma unroll
      for (int c = 0; c < 7; ++c){
        s += xr[c] * prep[54 + h * 7 + c];
        d += xr[c] * prep[82 + h * 7 + c];
      }
      sp[h] = s; dp[h] = d;
    }
    *(float4*)&sterm[(size_t)i * 4] = sv;
    *(float4*)&dterm[(size_t)i * 4] = dv;
  }
}

// ---------------- layer-1 aggregation, rank-7 factorized; fp16 output ----------------
__global__ __launch_bounds__(256) void k_agg4_l1(
    const float* __restrict__ xp, const float* __restrict__ sterm,
    const float* __restrict__ dterm, const float4* __restrict__ et1c,
    const int* __restrict__ row_off, const int* __restrict__ csr_src,
    const float* __restrict__ W1, const float* __restrict__ bias,
    u16* __restrict__ outA, int n){
  __shared__ float ps[4][MAXD][4];
  __shared__ float xv[4][MAXD][8];
  __shared__ float agg[4][4][8];
  int t = threadIdx.x, wv = t >> 6, l = t & 63;
  int i = blockIdx.x * 4 + wv;
  if (i >= n) return;
  int start = row_off[i], end = row_off[i + 1];
  int deg = end - start;
  if (deg > MAXD) deg = MAXD;
  float4 dt = *(const float4*)&dterm[(size_t)i * 4];
  float m0 = -1e30f, m1 = -1e30f, m2 = -1e30f, m3 = -1e30f;
  for (int k = l; k < deg; k += 64){
    int s = csr_src[start + k];
    float4 xA = *(const float4*)&xp[(size_t)s * 8];
    float4 xB = *(const float4*)&xp[(size_t)s * 8 + 4];
    *(float4*)&xv[wv][k][0] = xA;
    *(float4*)&xv[wv][k][4] = xB;
    float4 st = *(const float4*)&sterm[(size_t)s * 4];
    float4 et = et1c[start + k];
    float ax = st.x + dt.x + et.x;
    float ay = st.y + dt.y + et.y;
    float az = st.z + dt.z + et.z;
    float aw = st.w + dt.w + et.w;
    ax = (ax > 0.f) ? ax : LRELU_SLOPE * ax;
    ay = (ay > 0.f) ? ay : LRELU_SLOPE * ay;
    az = (az > 0.f) ? az : LRELU_SLOPE * az;
    aw = (aw > 0.f) ? aw : LRELU_SLOPE * aw;
    *(float4*)&ps[wv][k][0] = make_float4(ax, ay, az, aw);
    m0 = fmaxf(m0, ax); m1 = fmaxf(m1, ay); m2 = fmaxf(m2, az); m3 = fmaxf(m3, aw);
  }
  m0 = wave_reduce_max(m0); m1 = wave_reduce_max(m1);
  m2 = wave_reduce_max(m2); m3 = wave_reduce_max(m3);
  float d0 = 0.f, d1 = 0.f, d2 = 0.f, d3 = 0.f;
  for (int k = l; k < deg; k += 64){
    float4 a = *(const float4*)&ps[wv][k][0];
    float e0 = __expf(a.x - m0), e1 = __expf(a.y - m1);
    float e2 = __expf(a.z - m2), e3 = __expf(a.w - m3);
    *(float4*)&ps[wv][k][0] = make_float4(e0, e1, e2, e3);
    d0 += e0; d1 += e1; d2 += e2; d3 += e3;
  }
  d0 = wave_reduce_sum(d0); d1 = wave_reduce_sum(d1);
  d2 = wave_reduce_sum(d2); d3 = wave_reduce_sum(d3);
  float i0 = 1.0f / (d0 + 1e-16f), i1 = 1.0f / (d1 + 1e-16f);
  float i2 = 1.0f / (d2 + 1e-16f), i3 = 1.0f / (d3 + 1e-16f);
  // phase B: 56 active lanes, 2 k-stripes; lane (l&31)<28 owns (h,c)
  int q28 = l & 31, stripe = l >> 5;
  float a = 0.f;
  if (q28 < 28){
    int h = q28 / 7, c = q28 % 7;
    for (int k = stripe; k < deg; k += 2) a += ps[wv][k][h] * xv[wv][k][c];
  }
  a += __shfl_xor(a, 32, 64);
  if (l < 28){
    int h = l / 7, c = l % 7;
    float inv = (h == 0) ? i0 : (h == 1) ? i1 : (h == 2) ? i2 : i3;
    agg[wv][h][c] = a * inv;
  }
  int h2 = l >> 4;
  float av[7];
  #pragma unroll
  for (int c = 0; c < 7; ++c) av[c] = agg[wv][h2][c];
  float4 bi = *(const float4*)&bias[4 * l];
  float o0 = bi.x, o1 = bi.y, o2 = bi.z, o3 = bi.w;
  #pragma unroll
  for (int c = 0; c < 7; ++c){
    float4 wc = *(const float4*)&W1[c * 256 + 4 * l];
    o0 += av[c] * wc.x; o1 += av[c] * wc.y;
    o2 += av[c] * wc.z; o3 += av[c] * wc.w;
  }
  o0 = (o0 > 0.f) ? o0 : (__expf(o0) - 1.0f);
  o1 = (o1 > 0.f) ? o1 : (__expf(o1) - 1.0f);
  o2 = (o2 > 0.f) ? o2 : (__expf(o2) - 1.0f);
  o3 = (o3 > 0.f) ? o3 : (__expf(o3) - 1.0f);
  bh4 ho = { f2h(o0), f2h(o1), f2h(o2), f2h(o3) };
  *(bh4*)&outA[(size_t)i * 256 + 4 * l] = ho;
}

// ---------------- MFMA GEMM fp16: [M x 256] x [256 x N] ----------------
template<int NF, int H>
__global__ __launch_bounds__(256) void k_gemm_mfma(
    const u16* __restrict__ A, const u16* __restrict__ Wt,
    u16* __restrict__ gbf, float* __restrict__ sterm, float* __restrict__ dterm,
    const float* __restrict__ a_s, const float* __restrict__ a_d){
  const int Ntot = NF * 64;
  __shared__ u16 sA[64 * 256];   // 32 KB, XOR-swizzled 16B chunks
  __shared__ float red[2][64][4];
  int tid = threadIdx.x;
  int w = tid >> 6, l = tid & 63;
  int lr = l & 15, lg = l >> 4;
  int m0 = blockIdx.x * 64;
  for (int c = tid; c < 2048; c += 256){
    int row = c >> 5, kc = c & 31;
    size_t gidx = (size_t)(m0 + row) * 256 + kc * 8;
    unsigned byt = (unsigned)(row * 512 + kc * 16) ^ ((unsigned)(row & 7) << 4);
    *(s8v*)((char*)sA + byt) = *(const s8v*)&A[gidx];
  }
  __syncthreads();
  f4v acc[4][NF];
  #pragma unroll
  for (int m = 0; m < 4; ++m)
    #pragma unroll
    for (int nf = 0; nf < NF; ++nf)
      #pragma unroll
      for (int r = 0; r < 4; ++r) acc[m][nf][r] = 0.f;

  #pragma unroll
  for (int ks = 0; ks < 8; ++ks){
    int k0 = ks * 32;
    h8v ah[4];
    #pragma unroll
    for (int m = 0; m < 4; ++m){
      int row = m * 16 + lr;
      unsigned byt = ((unsigned)(row * 512 + (k0 + 8 * lg) * 2)) ^ ((unsigned)(row & 7) << 4);
      ah[m] = *(const h8v*)((const char*)sA + byt);
    }
    #pragma unroll
    for (int nf = 0; nf < NF; ++nf){
      int col = w * (NF * 16) + nf * 16 + lr;
      h8v bh = *(const h8v*)&Wt[(size_t)col * 256 + k0 + 8 * lg];
      #pragma unroll
      for (int m = 0; m < 4; ++m){
        acc[m][nf] = __builtin_amdgcn_mfma_f32_16x16x32_f16(ah[m], bh, acc[m][nf], 0, 0, 0);
      }
    }
  }
  if (H == 4){
    #pragma unroll
    for (int m = 0; m < 4; ++m){
      #pragma unroll
      for (int r = 0; r < 4; ++r){
        int row = m0 + m * 16 + 4 * lg + r;
        float sv = 0.f, dv = 0.f;
        #pragma unroll
        for (int nf = 0; nf < NF; ++nf){
          float v = acc[m][nf][r];
          int c = w * 64 + nf * 16 + lr;
          gbf[(size_t)row * Ntot + c] = f2h(v);
          sv += v * a_s[c];
          dv += v * a_d[c];
        }
        sv = red16_sum(sv);
        dv = red16_sum(dv);
        if (lr == 0){ sterm[row * 4 + w] = sv; dterm[row * 4 + w] = dv; }
      }
    }
  } else {
    #pragma unroll
    for (int m = 0; m < 4; ++m){
      #pragma unroll
      for (int r = 0; r < 4; ++r){
        int rl = m * 16 + 4 * lg + r;
        float v = acc[m][0][r];
        int c = w * 16 + lr;
        gbf[(size_t)(m0 + rl) * Ntot + c] = f2h(v);
        float sv = red16_sum(v * a_s[c]);
        float dv = red16_sum(v * a_d[c]);
        if (lr == 0){ red[0][rl][w] = sv; red[1][rl][w] = dv; }
      }
    }
    __syncthreads();
    if (tid < 64){
      float s = 0.f, d = 0.f;
      #pragma unroll
      for (int ww = 0; ww < 4; ++ww){ s += red[0][tid][ww]; d += red[1][tid][ww]; }
      sterm[m0 + tid] = s; dterm[m0 + tid] = d;
    }
  }
}

// ---------------- aggregation: wave-per-node, fp16 gather, 16B/lane ----------------
__global__ __launch_bounds__(256) void k_agg4(
    const u16* __restrict__ g_bf, const float* __restrict__ sterm,
    const float* __restrict__ dterm, const float4* __restrict__ etc,
    const int* __restrict__ row_off, const int* __restrict__ csr_src,
    const float* __restrict__ bias,
    u16* __restrict__ outA, int n){
  __shared__ float ps[4][MAXD][4];
  __shared__ int ssrc[4][MAXD];
  int t = threadIdx.x;
  int wv = t >> 6, l = t & 63;
  int i = blockIdx.x * 4 + wv;
  if (i >= n) return;
  int start = row_off[i], end = row_off[i + 1];
  int deg = end - start;
  if (deg > MAXD) deg = MAXD;
  float4 dt = *(const float4*)&dterm[(size_t)i * 4];
  float m0 = -1e30f, m1 = -1e30f, m2 = -1e30f, m3 = -1e30f;
  for (int k = l; k < deg; k += 64){
    int s = csr_src[start + k];
    ssrc[wv][k] = s;
    float4 st = *(const float4*)&sterm[(size_t)s * 4];
    float4 et = etc[start + k];
    float ax = st.x + dt.x + et.x;
    float ay = st.y + dt.y + et.y;
    float az = st.z + dt.z + et.z;
    float aw = st.w + dt.w + et.w;
    ax = (ax > 0.f) ? ax : LRELU_SLOPE * ax;
    ay = (ay > 0.f) ? ay : LRELU_SLOPE * ay;
    az = (az > 0.f) ? az : LRELU_SLOPE * az;
    aw = (aw > 0.f) ? aw : LRELU_SLOPE * aw;
    *(float4*)&ps[wv][k][0] = make_float4(ax, ay, az, aw);
    m0 = fmaxf(m0, ax); m1 = fmaxf(m1, ay); m2 = fmaxf(m2, az); m3 = fmaxf(m3, aw);
  }
  m0 = wave_reduce_max(m0); m1 = wave_reduce_max(m1);
  m2 = wave_reduce_max(m2); m3 = wave_reduce_max(m3);
  float d0 = 0.f, d1 = 0.f, d2 = 0.f, d3 = 0.f;
  for (int k = l; k < deg; k += 64){
    float4 a = *(const float4*)&ps[wv][k][0];
    float e0 = __expf(a.x - m0), e1 = __expf(a.y - m1);
    float e2 = __expf(a.z - m2), e3 = __expf(a.w - m3);
    *(float4*)&ps[wv][k][0] = make_float4(e0, e1, e2, e3);
    d0 += e0; d1 += e1; d2 += e2; d3 += e3;
  }
  d0 = wave_reduce_sum(d0); d1 = wave_reduce_sum(d1);
  d2 = wave_reduce_sum(d2); d3 = wave_reduce_sum(d3);
  float i0 = 1.0f / (d0 + 1e-16f), i1 = 1.0f / (d1 + 1e-16f);
  float i2 = 1.0f / (d2 + 1e-16f), i3 = 1.0f / (d3 + 1e-16f);
  // phase 2: lane covers channels 8q..8q+7 (q=l&31); halves process edges k+sub
  int sub = l >> 5, q = l & 31;
  int h3 = q >> 3;
  float inv = (h3 == 0) ? i0 : (h3 == 1) ? i1 : (h3 == 2) ? i2 : i3;
  const char* gb = (const char*)g_bf + (q << 4);
  float a0=0.f,a1=0.f,a2=0.f,a3=0.f,a4=0.f,a5=0.f,a6=0.f,a7=0.f;
#define ACC8(P, V) \
  a0 += (P) * hlo((V).x); a1 += (P) * hhi((V).x); \
  a2 += (P) * hlo((V).y); a3 += (P) * hhi((V).y); \
  a4 += (P) * hlo((V).z); a5 += (P) * hhi((V).z); \
  a6 += (P) * hlo((V).w); a7 += (P) * hhi((V).w);
  int k = 0;
  for (; k + 7 < deg; k += 8){
    int s0 = ssrc[wv][k + sub],     s1 = ssrc[wv][k + 2 + sub];
    int s2 = ssrc[wv][k + 4 + sub], s3 = ssrc[wv][k + 6 + sub];
    float p0 = ps[wv][k + sub][h3],     p1 = ps[wv][k + 2 + sub][h3];
    float p2 = ps[wv][k + 4 + sub][h3], p3 = ps[wv][k + 6 + sub][h3];
    uint4 v0 = *(const uint4*)(gb + ((unsigned)s0 << 9));
    uint4 v1 = *(const uint4*)(gb + ((unsigned)s1 << 9));
    uint4 v2 = *(const uint4*)(gb + ((unsigned)s2 << 9));
    uint4 v3 = *(const uint4*)(gb + ((unsigned)s3 << 9));
    ACC8(p0, v0); ACC8(p1, v1); ACC8(p2, v2); ACC8(p3, v3);
  }
  for (; k < deg; k += 2){
    int kk = k + sub;
    if (kk < deg){
      int s = ssrc[wv][kk];
      float p = ps[wv][kk][h3];
      uint4 v = *(const uint4*)(gb + ((unsigned)s << 9));
      ACC8(p, v);
    }
  }
#undef ACC8
  a0 += __shfl_xor(a0, 32, 64); a1 += __shfl_xor(a1, 32, 64);
  a2 += __shfl_xor(a2, 32, 64); a3 += __shfl_xor(a3, 32, 64);
  a4 += __shfl_xor(a4, 32, 64); a5 += __shfl_xor(a5, 32, 64);
  a6 += __shfl_xor(a6, 32, 64); a7 += __shfl_xor(a7, 32, 64);
  if (sub == 0){
    float4 bA = *(const float4*)&bias[8 * q];
    float4 bB = *(const float4*)&bias[8 * q + 4];
    float o[8] = { a0 * inv + bA.x, a1 * inv + bA.y, a2 * inv + bA.z, a3 * inv + bA.w,
                   a4 * inv + bB.x, a5 * inv + bB.y, a6 * inv + bB.z, a7 * inv + bB.w };
    bh8 ho;
    #pragma unroll
    for (int j = 0; j < 8; ++j){
      float e = (o[j] > 0.f) ? o[j] : (__expf(o[j]) - 1.0f);
      ho.v[j] = f2h(e);
    }
    *(bh8*)&outA[(size_t)i * 256 + 8 * q] = ho;
  }
}

// H=1: wave-per-node; 16B/lane, 8 edges/wave
__global__ __launch_bounds__(256) void k_agg1(
    const u16* __restrict__ g_bf, const float* __restrict__ sterm,
    const float* __restrict__ dterm, const float* __restrict__ et3c,
    const int* __restrict__ row_off, const int* __restrict__ csr_src,
    const float* __restrict__ bias,
    float* __restrict__ fout, int n){
  __shared__ float ps1[4][MAXD];
  __shared__ int ss1[4][MAXD];
  int t = threadIdx.x;
  int wv = t >> 6, l = t & 63;
  int i = blockIdx.x * 4 + wv;
  if (i >= n) return;
  int start = row_off[i], end = row_off[i + 1];
  int deg = end - start;
  if (deg > MAXD) deg = MAXD;
  float dti = dterm[i];
  float mloc = -1e30f;
  for (int k = l; k < deg; k += 64){
    int s = csr_src[start + k];
    ss1[wv][k] = s;
    float a = sterm[s] + dti + et3c[start + k];
    a = (a > 0.f) ? a : LRELU_SLOPE * a;
    ps1[wv][k] = a;
    mloc = fmaxf(mloc, a);
  }
  mloc = wave_reduce_max(mloc);
  float den = 0.f;
  for (int k = l; k < deg; k += 64){
    float pe = __expf(ps1[wv][k] - mloc);
    ps1[wv][k] = pe;
    den += pe;
  }
  den = wave_reduce_sum(den);
  float inv = 1.0f / (den + 1e-16f);
  int q = l & 7, g8 = l >> 3;
  const char* gb = (const char*)g_bf + (q << 4);
  float a0=0.f,a1=0.f,a2=0.f,a3=0.f,a4=0.f,a5=0.f,a6=0.f,a7=0.f;
#define ACC8(P, V) \
  a0 += (P) * hlo((V).x); a1 += (P) * hhi((V).x); \
  a2 += (P) * hlo((V).y); a3 += (P) * hhi((V).y); \
  a4 += (P) * hlo((V).z); a5 += (P) * hhi((V).z); \
  a6 += (P) * hlo((V).w); a7 += (P) * hhi((V).w);
  int k = g8;
  for (; k + 8 < deg; k += 16){
    int s0 = ss1[wv][k], s1 = ss1[wv][k + 8];
    float p0 = ps1[wv][k], p1 = ps1[wv][k + 8];
    uint4 v0 = *(const uint4*)(gb + ((unsigned)s0 << 7));
    uint4 v1 = *(const uint4*)(gb + ((unsigned)s1 << 7));
    ACC8(p0, v0); ACC8(p1, v1);
  }
  for (; k < deg; k += 8){
    int s = ss1[wv][k];
    float p = ps1[wv][k];
    uint4 v = *(const uint4*)(gb + ((unsigned)s << 7));
    ACC8(p, v);
  }
#undef ACC8
  #pragma unroll
  for (int off = 8; off < 64; off <<= 1){
    a0 += __shfl_xor(a0, off, 64); a1 += __shfl_xor(a1, off, 64);
    a2 += __shfl_xor(a2, off, 64); a3 += __shfl_xor(a3, off, 64);
    a4 += __shfl_xor(a4, off, 64); a5 += __shfl_xor(a5, off, 64);
    a6 += __shfl_xor(a6, off, 64); a7 += __shfl_xor(a7, off, 64);
  }
  if (l < 8){
    int c8 = q * 8;
    float o[8] = { a0, a1, a2, a3, a4, a5, a6, a7 };
    #pragma unroll
    for (int j = 0; j < 8; ++j){
      float v = o[j] * inv + bias[c8 + j];
      o[j] = (v > 0.f) ? v : (__expf(v) - 1.0f);
    }
    *(float4*)&fout[(size_t)i * 64 + c8]     = make_float4(o[0], o[1], o[2], o[3]);
    *(float4*)&fout[(size_t)i * 64 + c8 + 4] = make_float4(o[4], o[5], o[6], o[7]);
  }
}

// fused readout + MLP
__global__ __launch_bounds__(256) void k_readout_mlp(
    const float* __restrict__ f3, const int* __restrict__ goff,
    const float* __restrict__ p1w, const float* __restrict__ p1b,
    const float* __restrict__ p2w, const float* __restrict__ p2b,
    const float* __restrict__ p3w, const float* __restrict__ p3b,
    float* __restrict__ ro, float* __restrict__ out){
  __shared__ float red[4][64];
  __shared__ float rr[64], z1[64], z2[32];
  int g = blockIdx.x, t = threadIdx.x;
  int wv = t >> 6, l = t & 63;
  int s = goff[g], e = goff[g + 1];
  float acc = 0.f;
  for (int i = s + wv; i < e; i += 4) acc += f3[(size_t)i * 64 + l];
  red[wv][l] = acc;
  __syncthreads();
  if (t < 64){
    float r = (red[0][t] + red[1][t] + red[2][t] + red[3][t]) / fmaxf((float)(e - s), 1.0f);
    ro[g * 64 + t] = r;
    rr[t] = r;
  }
  __syncthreads();
  if (t < 64){
    float a1 = p1b[t];
    for (int k = 0; k < 64; ++k) a1 += rr[k] * p1w[k * 64 + t];
    z1[t] = fmaxf(a1, 0.f);
  }
  __syncthreads();
  if (t < 32){
    float a2 = p2b[t];
    for (int k = 0; k < 64; ++k) a2 += z1[k] * p2w[k * 32 + t];
    z2[t] = fmaxf(a2, 0.f);
  }
  __syncthreads();
  if (t < 32){
    float v = z2[t] * p3w[t];
    #pragma unroll
    for (int off = 16; off; off >>= 1) v += __shfl_down(v, off, 64);
    if (t == 0) out[g] = v + p3b[0];
  }
}

extern "C" void kernel_launch(void* const* d_in, const int* in_sizes, int n_in,
                              void* d_out, int out_size, void* d_ws, size_t ws_size,
                              hipStream_t stream){
  const float* x          = (const float*)d_in[0];
  const int*   edge_index = (const int*)d_in[1];
  const float* edge_attr  = (const float*)d_in[2];
  const int*   batch      = (const int*)d_in[3];
  const float* W1  = (const float*)d_in[4];
  const float* We1 = (const float*)d_in[5];
  const float* a_s1= (const float*)d_in[6];
  const float* a_d1= (const float*)d_in[7];
  const float* a_e1= (const float*)d_in[8];
  const float* b1  = (const float*)d_in[9];
  const float* W2  = (const float*)d_in[10];
  const float* We2 = (const float*)d_in[11];
  const float* a_s2= (const float*)d_in[12];
  const float* a_d2= (const float*)d_in[13];
  const float* a_e2= (const float*)d_in[14];
  const float* b2  = (const float*)d_in[15];
  const float* W3  = (const float*)d_in[16];
  const float* We3 = (const float*)d_in[17];
  const float* a_s3= (const float*)d_in[18];
  const float* a_d3= (const float*)d_in[19];
  const float* a_e3= (const float*)d_in[20];
  const float* b3  = (const float*)d_in[21];
  const float* p1w = (const float*)d_in[22];
  const float* p1b = (const float*)d_in[23];
  const float* p2w = (const float*)d_in[24];
  const float* p2b = (const float*)d_in[25];
  const float* p3w = (const float*)d_in[26];
  const float* p3b = (const float*)d_in[27];

  const int n  = in_sizes[0] / 7;     // 40000
  const int E  = in_sizes[1] / 2;     // 640000
  const int Ef = E + n;               // 680000
  const int G  = out_size / 65;       // 128

  const int* src0 = edge_index;
  const int* dst0 = edge_index + E;

  char* wsb = (char*)d_ws;
  size_t off = 0;
  auto alloc = [&](size_t bytes) -> void* {
    void* p = wsb + off; off += (bytes + 255) & ~(size_t)255; return p;
  };
  u16*   Af16    = (u16*)alloc((size_t)n * 256 * 2);
  u16*   gbf     = (u16*)alloc((size_t)n * 256 * 2);
  float* bufB    = (float*)alloc((size_t)n * 64 * 4);
  float* sterm   = (float*)alloc((size_t)n * 4 * 4);
  float* dterm   = (float*)alloc((size_t)n * 4 * 4);
  float4* et1c   = (float4*)alloc((size_t)Ef * 16);
  float4* et2c   = (float4*)alloc((size_t)Ef * 16);
  float* et3c    = (float*)alloc((size_t)Ef * 4);
  float* xp      = (float*)alloc((size_t)n * 8 * 4);
  int*   indeg   = (int*)alloc((size_t)n * 4);   // contiguous with cursor for one memset
  int*   cursor  = (int*)alloc((size_t)n * 4);
  int*   row_off = (int*)alloc((size_t)(n + 1) * 4);
  int*   csr_src = (int*)alloc((size_t)Ef * 4);
  int*   csr_eid = (int*)alloc((size_t)Ef * 4);
  float* prep    = (float*)alloc(128 * 4);
  int*   goff    = (int*)alloc((size_t)(G + 1) * 4);
  int*   bsum    = (int*)alloc(64 * 4);
  u16*   Wt2     = (u16*)alloc((size_t)256 * 256 * 2);
  u16*   Wt3     = (u16*)alloc((size_t)64 * 256 * 2);
  (void)ws_size; (void)n_in;

  hipMemsetAsync(indeg, 0, (size_t)n * 4 * 2, stream);   // indeg + cursor

  const int TB = 256;
  const int SB = (n + SCAN_VPB - 1) / SCAN_VPB;   // 20 for n=40000
  const int FB = 321 + (E + TB - 1) / TB;
  k_front<<<FB, 256, 0, stream>>>(W2, W3, Wt2, Wt3,
                                  W1, a_s1, a_d1, We1, a_e1, We2, a_e2, We3, a_e3, prep,
                                  dst0, E, indeg, batch, n, G, goff);
  k_scan_local<<<SB, 256, 0, stream>>>(indeg, row_off, bsum, n, 1);
  k_scan_add<<<SB, 256, 0, stream>>>(row_off, bsum, n);
  k_scatter<<<(Ef + TB - 1) / TB, TB, 0, stream>>>(src0, dst0, E, n, row_off, cursor, csr_src, csr_eid);
  k_eterm_csr<<<(Ef + n + TB - 1) / TB, TB, 0, stream>>>(csr_eid, row_off, edge_attr, prep, x,
                                                         et1c, et2c, et3c, sterm, dterm, xp, E, Ef, n);

  // ---- Layer 1 (H=4), rank-7 factorized ----
  k_agg4_l1<<<(n + 3) / 4, 256, 0, stream>>>(xp, sterm, dterm, et1c, row_off, csr_src,
                                             W1, b1, Af16, n);

  // ---- Layer 2 (H=4) ----
  k_gemm_mfma<4, 4><<<n / 64, 256, 0, stream>>>(Af16, Wt2, gbf, sterm, dterm, a_s2, a_d2);
  k_agg4<<<(n + 3) / 4, 256, 0, stream>>>(gbf, sterm, dterm, et2c, row_off, csr_src, b2, Af16, n);

  // ---- Layer 3 (H=1) ----
  k_gemm_mfma<1, 1><<<n / 64, 256, 0, stream>>>(Af16, Wt3, gbf, sterm, dterm, a_s3, a_d3);
  k_agg1<<<(n + 3) / 4, 256, 0, stream>>>(gbf, sterm, dterm, et3c, row_off, csr_src, b3, bufB, n);

  // ---- readout + MLP ----  d_out layout: [out(G)] [readout(G*64)]
  float* out_scalar = (float*)d_out;
  float* out_ro = out_scalar + G;
  k_readout_mlp<<<G, 256, 0, stream>>>(bufB, goff, p1w, p1b, p2w, p2b, p3w, p3b, out_ro, out_scalar);
}

// Round 11
// 300.429 us; speedup vs baseline: 1.0230x; 1.0230x over previous
//
#include <hip/hip_runtime.h>
#include <hip/hip_fp16.h>
#include <math.h>

#define LRELU_SLOPE 0.2f
#define MAXD 128
#define SCAN_VPB 2048

typedef unsigned short u16;
struct __align__(8) bh4 { u16 x, y, z, w; };
struct __align__(16) bh8 { u16 v[8]; };
typedef __attribute__((ext_vector_type(8))) short s8v;       // 16B copy unit
typedef __attribute__((ext_vector_type(8))) _Float16 h8v;    // MFMA f16 operand
typedef __attribute__((ext_vector_type(4))) float f4v;       // MFMA acc

__device__ __forceinline__ u16 f2h(float f){
  _Float16 h = (_Float16)f;
  return *(u16*)&h;
}
__device__ __forceinline__ float h2f(u16 u){
  _Float16 h = *(_Float16*)&u;
  return (float)h;
}
__device__ __forceinline__ float hlo(unsigned u){ return h2f((u16)(u & 0xFFFFu)); }
__device__ __forceinline__ float hhi(unsigned u){ return h2f((u16)(u >> 16)); }

__device__ __forceinline__ float wave_reduce_max(float v){
  #pragma unroll
  for (int off = 32; off; off >>= 1) v = fmaxf(v, __shfl_xor(v, off, 64));
  return v;
}
__device__ __forceinline__ float wave_reduce_sum(float v){
  #pragma unroll
  for (int off = 32; off; off >>= 1) v += __shfl_xor(v, off, 64);
  return v;
}
__device__ __forceinline__ float red16_sum(float v){
  #pragma unroll
  for (int off = 1; off < 16; off <<= 1) v += __shfl_xor(v, off, 64);
  return v;
}

// ---------------- front: weight fp16 transpose + attn projections + count + goff ----------------
// prep layout: [0..53] proj(f*9+j), [54..81] as1p(h*7+c), [82..109] ad1p(h*7+c)
__global__ __launch_bounds__(256) void k_front(
    const float* __restrict__ W2, const float* __restrict__ W3,
    u16* __restrict__ Wt2, u16* __restrict__ Wt3,
    const float* __restrict__ W1, const float* __restrict__ as1, const float* __restrict__ ad1,
    const float* __restrict__ We1, const float* __restrict__ ae1,
    const float* __restrict__ We2, const float* __restrict__ ae2,
    const float* __restrict__ We3, const float* __restrict__ ae3,
    float* __restrict__ prep,
    const int* __restrict__ dst, int E, int* __restrict__ indeg,
    const int* __restrict__ batch, int n, int G, int* __restrict__ goff){
  int b = blockIdx.x, k = threadIdx.x;
  if (b < 256){
    Wt2[(size_t)b * 256 + k] = f2h(W2[(size_t)k * 256 + b]);
  } else if (b < 320){
    int c = b - 256;
    Wt3[(size_t)c * 256 + k] = f2h(W3[(size_t)k * 64 + c]);
  } else if (b == 320){
    int wv = k >> 6, l = k & 63;
    for (int task = wv; task < 110; task += 4){
      float v;
      if (task < 54){
        int f = task / 9, j = task % 9;
        if (j < 4)      v = We1[f * 256 + j * 64 + l] * ae1[j * 64 + l];
        else if (j < 8) v = We2[f * 256 + (j - 4) * 64 + l] * ae2[(j - 4) * 64 + l];
        else            v = We3[f * 64 + l] * ae3[l];
      } else if (task < 82){
        int q = task - 54; int h = q / 7, c = q % 7;
        v = W1[c * 256 + h * 64 + l] * as1[h * 64 + l];
      } else {
        int q = task - 82; int h = q / 7, c = q % 7;
        v = W1[c * 256 + h * 64 + l] * ad1[h * 64 + l];
      }
      float s = wave_reduce_sum(v);
      if (l == 0) prep[task] = s;
    }
  } else {
    int e = (b - 321) * 256 + k;
    if (e < E) atomicAdd(&indeg[dst[e]], 1);
    if (e < n){
      int bb = batch[e];
      if (e == 0){
        for (int g = 0; g <= bb; ++g) goff[g] = 0;
      } else {
        int pb = batch[e - 1];
        for (int g = pb + 1; g <= bb; ++g) goff[g] = e;
      }
      if (e == n - 1){
        for (int g = bb + 1; g <= G; ++g) goff[g] = n;
      }
    }
  }
}
__global__ __launch_bounds__(256) void k_scan_local(const int* __restrict__ in, int* __restrict__ out,
                                                    int* __restrict__ bsum, int n, int add_k){
  __shared__ int ts[256];
  int b = blockIdx.x, t = threadIdx.x;
  int base = b * SCAN_VPB;
  int vals[8]; int s = 0;
  #pragma unroll
  for (int j = 0; j < 8; ++j){
    int idx = base + t * 8 + j;
    int v = (idx < n) ? (in[idx] + add_k) : 0;
    vals[j] = v; s += v;
  }
  ts[t] = s; __syncthreads();
  #pragma unroll
  for (int off = 1; off < 256; off <<= 1){
    int x = (t >= off) ? ts[t - off] : 0;
    __syncthreads();
    ts[t] += x;
    __syncthreads();
  }
  int excl = t ? ts[t - 1] : 0;
  #pragma unroll
  for (int j = 0; j < 8; ++j){
    excl += vals[j];
    int idx = base + t * 8 + j;
    if (idx < n) out[idx + 1] = excl;
  }
  if (b == 0 && t == 0) out[0] = 0;
  if (t == 255 && bsum) bsum[b] = ts[255];
}
__global__ void k_scan_tops(const int* __restrict__ bsum, int* __restrict__ boff, int B){
  int t = threadIdx.x;  // 64
  int v = (t < B) ? bsum[t] : 0;
  int orig = v;
  #pragma unroll
  for (int off = 1; off < 64; off <<= 1){
    int x = __shfl_up(v, off, 64);
    if (t >= off) v += x;
  }
  if (t < B) boff[t] = v - orig;
}
__global__ __launch_bounds__(256) void k_scan_add(int* __restrict__ out, const int* __restrict__ boff, int n){
  int b = blockIdx.x, t = threadIdx.x;
  int add = boff[b];
  if (add == 0) return;
  int base = b * SCAN_VPB;
  #pragma unroll
  for (int j = 0; j < 8; ++j){
    int idx = base + t + j * 256;
    if (idx < n) out[idx + 1] += add;
  }
}
// scatter real edges + self-loops; separate src / eid arrays
__global__ void k_scatter(const int* __restrict__ src0, const int* __restrict__ dst0, int E, int n,
                          const int* __restrict__ row_off, int* __restrict__ cursor,
                          int* __restrict__ csr_src, int* __restrict__ csr_eid){
  int e = blockIdx.x * blockDim.x + threadIdx.x;
  if (e < E){
    int d = dst0[e];
    int pos = row_off[d] + atomicAdd(&cursor[d], 1);
    csr_src[pos] = src0[e];
    csr_eid[pos] = e;
  } else if (e < E + n){
    int i = e - E;
    int pos = row_off[i + 1] - 1;
    csr_src[pos] = i;
    csr_eid[pos] = E + i;
  }
}
// wave-per-node loop_attr (no sort needed; threshold-based validation tolerates reorder jitter)
__global__ __launch_bounds__(256) void k_loopattr(
    int n, const int* __restrict__ row_off, const int* __restrict__ csr_eid,
    const float* __restrict__ edge_attr, float* __restrict__ loop_attr){
  int t = threadIdx.x, wv = t >> 6, l = t & 63;
  int i = blockIdx.x * 4 + wv;
  if (i >= n) return;
  int s0 = row_off[i], e0 = row_off[i + 1] - 1;  // exclude self-loop slot
  int dr = e0 - s0;
  float a0=0.f,a1=0.f,a2=0.f,a3=0.f,a4=0.f,a5=0.f;
  for (int k = l; k < dr; k += 64){
    const float* p = &edge_attr[(size_t)csr_eid[s0 + k] * 6];
    a0 += p[0]; a1 += p[1]; a2 += p[2]; a3 += p[3]; a4 += p[4]; a5 += p[5];
  }
  a0 = wave_reduce_sum(a0); a1 = wave_reduce_sum(a1); a2 = wave_reduce_sum(a2);
  a3 = wave_reduce_sum(a3); a4 = wave_reduce_sum(a4); a5 = wave_reduce_sum(a5);
  if (l == 0){
    float inv = 1.0f / fmaxf((float)dr, 1.0f);
    float* lp = &loop_attr[(size_t)i * 6];
    lp[0]=a0*inv; lp[1]=a1*inv; lp[2]=a2*inv; lp[3]=a3*inv; lp[4]=a4*inv; lp[5]=a5*inv;
  }
}

// eterm in CSR order (coalesced writes; agg phase-1 then reads coalesced) + layer-1 sd + padded x
__global__ void k_eterm_csr(const int* __restrict__ csr_eid,
                            const float* __restrict__ ea, const float* __restrict__ lattr,
                            const float* __restrict__ prep, const float* __restrict__ x,
                            float4* __restrict__ et1c, float4* __restrict__ et2c,
                            float* __restrict__ et3c,
                            float* __restrict__ sterm, float* __restrict__ dterm,
                            float* __restrict__ xp,
                            int E, int Ef, int n){
  int pos = blockIdx.x * blockDim.x + threadIdx.x;
  if (pos < Ef){
    int eid = csr_eid[pos];
    const float* p = (eid < E) ? (ea + (size_t)eid * 6) : (lattr + (size_t)(eid - E) * 6);
    float acc[9] = {};
    #pragma unroll
    for (int f = 0; f < 6; ++f){
      float v = p[f];
      #pragma unroll
      for (int j = 0; j < 9; ++j) acc[j] += v * prep[f * 9 + j];
    }
    et1c[pos] = make_float4(acc[0], acc[1], acc[2], acc[3]);
    et2c[pos] = make_float4(acc[4], acc[5], acc[6], acc[7]);
    et3c[pos] = acc[8];
  } else if (pos < Ef + n){
    int i = pos - Ef;
    float xr[8];
    #pragma unroll
    for (int c = 0; c < 7; ++c) xr[c] = x[(size_t)i * 7 + c];
    xr[7] = 0.f;
    *(float4*)&xp[(size_t)i * 8] = make_float4(xr[0], xr[1], xr[2], xr[3]);
    *(float4*)&xp[(size_t)i * 8 + 4] = make_float4(xr[4], xr[5], xr[6], xr[7]);
    float4 sv, dv;
    float* sp = (float*)&sv; float* dp = (float*)&dv;
    #pragma unroll
    for (int h = 0; h < 4; ++h){
      float s = 0.f, d = 0.f;
      #pragma unroll
      for (int c = 0; c < 7; ++c){
        s += xr[c] * prep[54 + h * 7 + c];
        d += xr[c] * prep[82 + h * 7 + c];
      }
      sp[h] = s; dp[h] = d;
    }
    *(float4*)&sterm[(size_t)i * 4] = sv;
    *(float4*)&dterm[(size_t)i * 4] = dv;
  }
}

// ---------------- layer-1 aggregation, rank-7 factorized; fp16 output ----------------
__global__ __launch_bounds__(256) void k_agg4_l1(
    const float* __restrict__ xp, const float* __restrict__ sterm,
    const float* __restrict__ dterm, const float4* __restrict__ et1c,
    const int* __restrict__ row_off, const int* __restrict__ csr_src,
    const float* __restrict__ W1, const float* __restrict__ bias,
    u16* __restrict__ outA, int n){
  __shared__ float ps[4][MAXD][4];
  __shared__ float xv[4][MAXD][8];
  __shared__ float agg[4][4][8];
  int t = threadIdx.x, wv = t >> 6, l = t & 63;
  int i = blockIdx.x * 4 + wv;
  if (i >= n) return;
  int start = row_off[i], end = row_off[i + 1];
  int deg = end - start;
  if (deg > MAXD) deg = MAXD;
  float4 dt = *(const float4*)&dterm[(size_t)i * 4];
  float m0 = -1e30f, m1 = -1e30f, m2 = -1e30f, m3 = -1e30f;
  for (int k = l; k < deg; k += 64){
    int s = csr_src[start + k];
    float4 xA = *(const float4*)&xp[(size_t)s * 8];
    float4 xB = *(const float4*)&xp[(size_t)s * 8 + 4];
    *(float4*)&xv[wv][k][0] = xA;
    *(float4*)&xv[wv][k][4] = xB;
    float4 st = *(const float4*)&sterm[(size_t)s * 4];
    float4 et = et1c[start + k];
    float ax = st.x + dt.x + et.x;
    float ay = st.y + dt.y + et.y;
    float az = st.z + dt.z + et.z;
    float aw = st.w + dt.w + et.w;
    ax = (ax > 0.f) ? ax : LRELU_SLOPE * ax;
    ay = (ay > 0.f) ? ay : LRELU_SLOPE * ay;
    az = (az > 0.f) ? az : LRELU_SLOPE * az;
    aw = (aw > 0.f) ? aw : LRELU_SLOPE * aw;
    *(float4*)&ps[wv][k][0] = make_float4(ax, ay, az, aw);
    m0 = fmaxf(m0, ax); m1 = fmaxf(m1, ay); m2 = fmaxf(m2, az); m3 = fmaxf(m3, aw);
  }
  m0 = wave_reduce_max(m0); m1 = wave_reduce_max(m1);
  m2 = wave_reduce_max(m2); m3 = wave_reduce_max(m3);
  float d0 = 0.f, d1 = 0.f, d2 = 0.f, d3 = 0.f;
  for (int k = l; k < deg; k += 64){
    float4 a = *(const float4*)&ps[wv][k][0];
    float e0 = __expf(a.x - m0), e1 = __expf(a.y - m1);
    float e2 = __expf(a.z - m2), e3 = __expf(a.w - m3);
    *(float4*)&ps[wv][k][0] = make_float4(e0, e1, e2, e3);
    d0 += e0; d1 += e1; d2 += e2; d3 += e3;
  }
  d0 = wave_reduce_sum(d0); d1 = wave_reduce_sum(d1);
  d2 = wave_reduce_sum(d2); d3 = wave_reduce_sum(d3);
  float i0 = 1.0f / (d0 + 1e-16f), i1 = 1.0f / (d1 + 1e-16f);
  float i2 = 1.0f / (d2 + 1e-16f), i3 = 1.0f / (d3 + 1e-16f);
  if (l < 28){
    int h = l / 7, c = l % 7;
    float a = 0.f;
    for (int k = 0; k < deg; ++k) a += ps[wv][k][h] * xv[wv][k][c];
    float inv = (h == 0) ? i0 : (h == 1) ? i1 : (h == 2) ? i2 : i3;
    agg[wv][h][c] = a * inv;
  }
  int h2 = l >> 4;
  float av[7];
  #pragma unroll
  for (int c = 0; c < 7; ++c) av[c] = agg[wv][h2][c];
  float4 bi = *(const float4*)&bias[4 * l];
  float o0 = bi.x, o1 = bi.y, o2 = bi.z, o3 = bi.w;
  #pragma unroll
  for (int c = 0; c < 7; ++c){
    float4 wc = *(const float4*)&W1[c * 256 + 4 * l];
    o0 += av[c] * wc.x; o1 += av[c] * wc.y;
    o2 += av[c] * wc.z; o3 += av[c] * wc.w;
  }
  o0 = (o0 > 0.f) ? o0 : (__expf(o0) - 1.0f);
  o1 = (o1 > 0.f) ? o1 : (__expf(o1) - 1.0f);
  o2 = (o2 > 0.f) ? o2 : (__expf(o2) - 1.0f);
  o3 = (o3 > 0.f) ? o3 : (__expf(o3) - 1.0f);
  bh4 ho = { f2h(o0), f2h(o1), f2h(o2), f2h(o3) };
  *(bh4*)&outA[(size_t)i * 256 + 4 * l] = ho;
}

// ---------------- MFMA GEMM fp16: [M x 256] x [256 x N] ----------------
template<int NF, int H>
__global__ __launch_bounds__(256) void k_gemm_mfma(
    const u16* __restrict__ A, const u16* __restrict__ Wt,
    u16* __restrict__ gbf, float* __restrict__ sterm, float* __restrict__ dterm,
    const float* __restrict__ a_s, const float* __restrict__ a_d){
  const int Ntot = NF * 64;
  __shared__ u16 sA[64 * 256];   // 32 KB, XOR-swizzled 16B chunks
  __shared__ float red[2][64][4];
  int tid = threadIdx.x;
  int w = tid >> 6, l = tid & 63;
  int lr = l & 15, lg = l >> 4;
  int m0 = blockIdx.x * 64;
  for (int c = tid; c < 2048; c += 256){
    int row = c >> 5, kc = c & 31;
    size_t gidx = (size_t)(m0 + row) * 256 + kc * 8;
    unsigned byt = (unsigned)(row * 512 + kc * 16) ^ ((unsigned)(row & 7) << 4);
    *(s8v*)((char*)sA + byt) = *(const s8v*)&A[gidx];
  }
  __syncthreads();
  f4v acc[4][NF];
  #pragma unroll
  for (int m = 0; m < 4; ++m)
    #pragma unroll
    for (int nf = 0; nf < NF; ++nf)
      #pragma unroll
      for (int r = 0; r < 4; ++r) acc[m][nf][r] = 0.f;

  #pragma unroll
  for (int ks = 0; ks < 8; ++ks){
    int k0 = ks * 32;
    h8v ah[4];
    #pragma unroll
    for (int m = 0; m < 4; ++m){
      int row = m * 16 + lr;
      unsigned byt = ((unsigned)(row * 512 + (k0 + 8 * lg) * 2)) ^ ((unsigned)(row & 7) << 4);
      ah[m] = *(const h8v*)((const char*)sA + byt);
    }
    #pragma unroll
    for (int nf = 0; nf < NF; ++nf){
      int col = w * (NF * 16) + nf * 16 + lr;
      h8v bh = *(const h8v*)&Wt[(size_t)col * 256 + k0 + 8 * lg];
      #pragma unroll
      for (int m = 0; m < 4; ++m){
        acc[m][nf] = __builtin_amdgcn_mfma_f32_16x16x32_f16(ah[m], bh, acc[m][nf], 0, 0, 0);
      }
    }
  }
  if (H == 4){
    #pragma unroll
    for (int m = 0; m < 4; ++m){
      #pragma unroll
      for (int r = 0; r < 4; ++r){
        int row = m0 + m * 16 + 4 * lg + r;
        float sv = 0.f, dv = 0.f;
        #pragma unroll
        for (int nf = 0; nf < NF; ++nf){
          float v = acc[m][nf][r];
          int c = w * 64 + nf * 16 + lr;
          gbf[(size_t)row * Ntot + c] = f2h(v);
          sv += v * a_s[c];
          dv += v * a_d[c];
        }
        sv = red16_sum(sv);
        dv = red16_sum(dv);
        if (lr == 0){ sterm[row * 4 + w] = sv; dterm[row * 4 + w] = dv; }
      }
    }
  } else {
    #pragma unroll
    for (int m = 0; m < 4; ++m){
      #pragma unroll
      for (int r = 0; r < 4; ++r){
        int rl = m * 16 + 4 * lg + r;
        float v = acc[m][0][r];
        int c = w * 16 + lr;
        gbf[(size_t)(m0 + rl) * Ntot + c] = f2h(v);
        float sv = red16_sum(v * a_s[c]);
        float dv = red16_sum(v * a_d[c]);
        if (lr == 0){ red[0][rl][w] = sv; red[1][rl][w] = dv; }
      }
    }
    __syncthreads();
    if (tid < 64){
      float s = 0.f, d = 0.f;
      #pragma unroll
      for (int ww = 0; ww < 4; ++ww){ s += red[0][tid][ww]; d += red[1][tid][ww]; }
      sterm[m0 + tid] = s; dterm[m0 + tid] = d;
    }
  }
}

// ---------------- aggregation: wave-per-node, fp16 gather, 16B/lane ----------------
__global__ __launch_bounds__(256) void k_agg4(
    const u16* __restrict__ g_bf, const float* __restrict__ sterm,
    const float* __restrict__ dterm, const float4* __restrict__ etc,
    const int* __restrict__ row_off, const int* __restrict__ csr_src,
    const float* __restrict__ bias,
    u16* __restrict__ outA, int n){
  __shared__ float ps[4][MAXD][4];
  __shared__ int ssrc[4][MAXD];
  int t = threadIdx.x;
  int wv = t >> 6, l = t & 63;
  int i = blockIdx.x * 4 + wv;
  if (i >= n) return;
  int start = row_off[i], end = row_off[i + 1];
  int deg = end - start;
  if (deg > MAXD) deg = MAXD;
  float4 dt = *(const float4*)&dterm[(size_t)i * 4];
  float m0 = -1e30f, m1 = -1e30f, m2 = -1e30f, m3 = -1e30f;
  for (int k = l; k < deg; k += 64){
    int s = csr_src[start + k];
    ssrc[wv][k] = s;
    float4 st = *(const float4*)&sterm[(size_t)s * 4];
    float4 et = etc[start + k];
    float ax = st.x + dt.x + et.x;
    float ay = st.y + dt.y + et.y;
    float az = st.z + dt.z + et.z;
    float aw = st.w + dt.w + et.w;
    ax = (ax > 0.f) ? ax : LRELU_SLOPE * ax;
    ay = (ay > 0.f) ? ay : LRELU_SLOPE * ay;
    az = (az > 0.f) ? az : LRELU_SLOPE * az;
    aw = (aw > 0.f) ? aw : LRELU_SLOPE * aw;
    *(float4*)&ps[wv][k][0] = make_float4(ax, ay, az, aw);
    m0 = fmaxf(m0, ax); m1 = fmaxf(m1, ay); m2 = fmaxf(m2, az); m3 = fmaxf(m3, aw);
  }
  m0 = wave_reduce_max(m0); m1 = wave_reduce_max(m1);
  m2 = wave_reduce_max(m2); m3 = wave_reduce_max(m3);
  float d0 = 0.f, d1 = 0.f, d2 = 0.f, d3 = 0.f;
  for (int k = l; k < deg; k += 64){
    float4 a = *(const float4*)&ps[wv][k][0];
    float e0 = __expf(a.x - m0), e1 = __expf(a.y - m1);
    float e2 = __expf(a.z - m2), e3 = __expf(a.w - m3);
    *(float4*)&ps[wv][k][0] = make_float4(e0, e1, e2, e3);
    d0 += e0; d1 += e1; d2 += e2; d3 += e3;
  }
  d0 = wave_reduce_sum(d0); d1 = wave_reduce_sum(d1);
  d2 = wave_reduce_sum(d2); d3 = wave_reduce_sum(d3);
  float i0 = 1.0f / (d0 + 1e-16f), i1 = 1.0f / (d1 + 1e-16f);
  float i2 = 1.0f / (d2 + 1e-16f), i3 = 1.0f / (d3 + 1e-16f);
  // phase 2: lane covers channels 8q..8q+7 (q=l&31); halves process edges k+sub
  int sub = l >> 5, q = l & 31;
  int h3 = q >> 3;
  float inv = (h3 == 0) ? i0 : (h3 == 1) ? i1 : (h3 == 2) ? i2 : i3;
  const char* gb = (const char*)g_bf + (q << 4);
  float a0=0.f,a1=0.f,a2=0.f,a3=0.f,a4=0.f,a5=0.f,a6=0.f,a7=0.f;
#define ACC8(P, V) \
  a0 += (P) * hlo((V).x); a1 += (P) * hhi((V).x); \
  a2 += (P) * hlo((V).y); a3 += (P) * hhi((V).y); \
  a4 += (P) * hlo((V).z); a5 += (P) * hhi((V).z); \
  a6 += (P) * hlo((V).w); a7 += (P) * hhi((V).w);
  int k = 0;
  for (; k + 7 < deg; k += 8){
    int s0 = ssrc[wv][k + sub],     s1 = ssrc[wv][k + 2 + sub];
    int s2 = ssrc[wv][k + 4 + sub], s3 = ssrc[wv][k + 6 + sub];
    float p0 = ps[wv][k + sub][h3],     p1 = ps[wv][k + 2 + sub][h3];
    float p2 = ps[wv][k + 4 + sub][h3], p3 = ps[wv][k + 6 + sub][h3];
    uint4 v0 = *(const uint4*)(gb + ((unsigned)s0 << 9));
    uint4 v1 = *(const uint4*)(gb + ((unsigned)s1 << 9));
    uint4 v2 = *(const uint4*)(gb + ((unsigned)s2 << 9));
    uint4 v3 = *(const uint4*)(gb + ((unsigned)s3 << 9));
    ACC8(p0, v0); ACC8(p1, v1); ACC8(p2, v2); ACC8(p3, v3);
  }
  for (; k < deg; k += 2){
    int kk = k + sub;
    if (kk < deg){
      int s = ssrc[wv][kk];
      float p = ps[wv][kk][h3];
      uint4 v = *(const uint4*)(gb + ((unsigned)s << 9));
      ACC8(p, v);
    }
  }
#undef ACC8
  a0 += __shfl_xor(a0, 32, 64); a1 += __shfl_xor(a1, 32, 64);
  a2 += __shfl_xor(a2, 32, 64); a3 += __shfl_xor(a3, 32, 64);
  a4 += __shfl_xor(a4, 32, 64); a5 += __shfl_xor(a5, 32, 64);
  a6 += __shfl_xor(a6, 32, 64); a7 += __shfl_xor(a7, 32, 64);
  if (sub == 0){
    float4 bA = *(const float4*)&bias[8 * q];
    float4 bB = *(const float4*)&bias[8 * q + 4];
    float o[8] = { a0 * inv + bA.x, a1 * inv + bA.y, a2 * inv + bA.z, a3 * inv + bA.w,
                   a4 * inv + bB.x, a5 * inv + bB.y, a6 * inv + bB.z, a7 * inv + bB.w };
    bh8 ho;
    #pragma unroll
    for (int j = 0; j < 8; ++j){
      float e = (o[j] > 0.f) ? o[j] : (__expf(o[j]) - 1.0f);
      ho.v[j] = f2h(e);
    }
    *(bh8*)&outA[(size_t)i * 256 + 8 * q] = ho;
  }
}

// H=1: wave-per-node; 16B/lane, 8 edges/wave
__global__ __launch_bounds__(256) void k_agg1(
    const u16* __restrict__ g_bf, const float* __restrict__ sterm,
    const float* __restrict__ dterm, const float* __restrict__ et3c,
    const int* __restrict__ row_off, const int* __restrict__ csr_src,
    const float* __restrict__ bias,
    float* __restrict__ fout, int n){
  __shared__ float ps1[4][MAXD];
  __shared__ int ss1[4][MAXD];
  int t = threadIdx.x;
  int wv = t >> 6, l = t & 63;
  int i = blockIdx.x * 4 + wv;
  if (i >= n) return;
  int start = row_off[i], end = row_off[i + 1];
  int deg = end - start;
  if (deg > MAXD) deg = MAXD;
  float dti = dterm[i];
  float mloc = -1e30f;
  for (int k = l; k < deg; k += 64){
    int s = csr_src[start + k];
    ss1[wv][k] = s;
    float a = sterm[s] + dti + et3c[start + k];
    a = (a > 0.f) ? a : LRELU_SLOPE * a;
    ps1[wv][k] = a;
    mloc = fmaxf(mloc, a);
  }
  mloc = wave_reduce_max(mloc);
  float den = 0.f;
  for (int k = l; k < deg; k += 64){
    float pe = __expf(ps1[wv][k] - mloc);
    ps1[wv][k] = pe;
    den += pe;
  }
  den = wave_reduce_sum(den);
  float inv = 1.0f / (den + 1e-16f);
  int q = l & 7, g8 = l >> 3;
  const char* gb = (const char*)g_bf + (q << 4);
  float a0=0.f,a1=0.f,a2=0.f,a3=0.f,a4=0.f,a5=0.f,a6=0.f,a7=0.f;
#define ACC8(P, V) \
  a0 += (P) * hlo((V).x); a1 += (P) * hhi((V).x); \
  a2 += (P) * hlo((V).y); a3 += (P) * hhi((V).y); \
  a4 += (P) * hlo((V).z); a5 += (P) * hhi((V).z); \
  a6 += (P) * hlo((V).w); a7 += (P) * hhi((V).w);
  int k = g8;
  for (; k + 8 < deg; k += 16){
    int s0 = ss1[wv][k], s1 = ss1[wv][k + 8];
    float p0 = ps1[wv][k], p1 = ps1[wv][k + 8];
    uint4 v0 = *(const uint4*)(gb + ((unsigned)s0 << 7));
    uint4 v1 = *(const uint4*)(gb + ((unsigned)s1 << 7));
    ACC8(p0, v0); ACC8(p1, v1);
  }
  for (; k < deg; k += 8){
    int s = ss1[wv][k];
    float p = ps1[wv][k];
    uint4 v = *(const uint4*)(gb + ((unsigned)s << 7));
    ACC8(p, v);
  }
#undef ACC8
  #pragma unroll
  for (int off = 8; off < 64; off <<= 1){
    a0 += __shfl_xor(a0, off, 64); a1 += __shfl_xor(a1, off, 64);
    a2 += __shfl_xor(a2, off, 64); a3 += __shfl_xor(a3, off, 64);
    a4 += __shfl_xor(a4, off, 64); a5 += __shfl_xor(a5, off, 64);
    a6 += __shfl_xor(a6, off, 64); a7 += __shfl_xor(a7, off, 64);
  }
  if (l < 8){
    int c8 = q * 8;
    float o[8] = { a0, a1, a2, a3, a4, a5, a6, a7 };
    #pragma unroll
    for (int j = 0; j < 8; ++j){
      float v = o[j] * inv + bias[c8 + j];
      o[j] = (v > 0.f) ? v : (__expf(v) - 1.0f);
    }
    *(float4*)&fout[(size_t)i * 64 + c8]     = make_float4(o[0], o[1], o[2], o[3]);
    *(float4*)&fout[(size_t)i * 64 + c8 + 4] = make_float4(o[4], o[5], o[6], o[7]);
  }
}

// fused readout + MLP
__global__ __launch_bounds__(256) void k_readout_mlp(
    const float* __restrict__ f3, const int* __restrict__ goff,
    const float* __restrict__ p1w, const float* __restrict__ p1b,
    const float* __restrict__ p2w, const float* __restrict__ p2b,
    const float* __restrict__ p3w, const float* __restrict__ p3b,
    float* __restrict__ ro, float* __restrict__ out){
  __shared__ float red[4][64];
  __shared__ float rr[64], z1[64], z2[32];
  int g = blockIdx.x, t = threadIdx.x;
  int wv = t >> 6, l = t & 63;
  int s = goff[g], e = goff[g + 1];
  float acc = 0.f;
  for (int i = s + wv; i < e; i += 4) acc += f3[(size_t)i * 64 + l];
  red[wv][l] = acc;
  __syncthreads();
  if (t < 64){
    float r = (red[0][t] + red[1][t] + red[2][t] + red[3][t]) / fmaxf((float)(e - s), 1.0f);
    ro[g * 64 + t] = r;
    rr[t] = r;
  }
  __syncthreads();
  if (t < 64){
    float a1 = p1b[t];
    for (int k = 0; k < 64; ++k) a1 += rr[k] * p1w[k * 64 + t];
    z1[t] = fmaxf(a1, 0.f);
  }
  __syncthreads();
  if (t < 32){
    float a2 = p2b[t];
    for (int k = 0; k < 64; ++k) a2 += z1[k] * p2w[k * 32 + t];
    z2[t] = fmaxf(a2, 0.f);
  }
  __syncthreads();
  if (t < 32){
    float v = z2[t] * p3w[t];
    #pragma unroll
    for (int off = 16; off; off >>= 1) v += __shfl_down(v, off, 64);
    if (t == 0) out[g] = v + p3b[0];
  }
}

extern "C" void kernel_launch(void* const* d_in, const int* in_sizes, int n_in,
                              void* d_out, int out_size, void* d_ws, size_t ws_size,
                              hipStream_t stream){
  const float* x          = (const float*)d_in[0];
  const int*   edge_index = (const int*)d_in[1];
  const float* edge_attr  = (const float*)d_in[2];
  const int*   batch      = (const int*)d_in[3];
  const float* W1  = (const float*)d_in[4];
  const float* We1 = (const float*)d_in[5];
  const float* a_s1= (const float*)d_in[6];
  const float* a_d1= (const float*)d_in[7];
  const float* a_e1= (const float*)d_in[8];
  const float* b1  = (const float*)d_in[9];
  const float* W2  = (const float*)d_in[10];
  const float* We2 = (const float*)d_in[11];
  const float* a_s2= (const float*)d_in[12];
  const float* a_d2= (const float*)d_in[13];
  const float* a_e2= (const float*)d_in[14];
  const float* b2  = (const float*)d_in[15];
  const float* W3  = (const float*)d_in[16];
  const float* We3 = (const float*)d_in[17];
  const float* a_s3= (const float*)d_in[18];
  const float* a_d3= (const float*)d_in[19];
  const float* a_e3= (const float*)d_in[20];
  const float* b3  = (const float*)d_in[21];
  const float* p1w = (const float*)d_in[22];
  const float* p1b = (const float*)d_in[23];
  const float* p2w = (const float*)d_in[24];
  const float* p2b = (const float*)d_in[25];
  const float* p3w = (const float*)d_in[26];
  const float* p3b = (const float*)d_in[27];

  const int n  = in_sizes[0] / 7;     // 40000
  const int E  = in_sizes[1] / 2;     // 640000
  const int Ef = E + n;               // 680000
  const int G  = out_size / 65;       // 128

  const int* src0 = edge_index;
  const int* dst0 = edge_index + E;

  char* wsb = (char*)d_ws;
  size_t off = 0;
  auto alloc = [&](size_t bytes) -> void* {
    void* p = wsb + off; off += (bytes + 255) & ~(size_t)255; return p;
  };
  u16*   Af16    = (u16*)alloc((size_t)n * 256 * 2);
  u16*   gbf     = (u16*)alloc((size_t)n * 256 * 2);
  float* bufB    = (float*)alloc((size_t)n * 64 * 4);
  float* sterm   = (float*)alloc((size_t)n * 4 * 4);
  float* dterm   = (float*)alloc((size_t)n * 4 * 4);
  float4* et1c   = (float4*)alloc((size_t)Ef * 16);
  float4* et2c   = (float4*)alloc((size_t)Ef * 16);
  float* et3c    = (float*)alloc((size_t)Ef * 4);
  float* lattr   = (float*)alloc((size_t)n * 6 * 4);
  float* xp      = (float*)alloc((size_t)n * 8 * 4);
  int*   indeg   = (int*)alloc((size_t)n * 4);   // contiguous with cursor for one memset
  int*   cursor  = (int*)alloc((size_t)n * 4);
  int*   row_off = (int*)alloc((size_t)(n + 1) * 4);
  int*   csr_src = (int*)alloc((size_t)Ef * 4);
  int*   csr_eid = (int*)alloc((size_t)Ef * 4);
  float* prep    = (float*)alloc(128 * 4);
  int*   goff    = (int*)alloc((size_t)(G + 1) * 4);
  int*   bsum    = (int*)alloc(64 * 4);
  int*   boff    = (int*)alloc(64 * 4);
  u16*   Wt2     = (u16*)alloc((size_t)256 * 256 * 2);
  u16*   Wt3     = (u16*)alloc((size_t)64 * 256 * 2);
  (void)ws_size; (void)n_in;

  hipMemsetAsync(indeg, 0, (size_t)n * 4 * 2, stream);   // indeg + cursor

  const int TB = 256;
  const int SB = (n + SCAN_VPB - 1) / SCAN_VPB;   // 20 for n=40000
  const int FB = 321 + (E + TB - 1) / TB;
  k_front<<<FB, 256, 0, stream>>>(W2, W3, Wt2, Wt3,
                                  W1, a_s1, a_d1, We1, a_e1, We2, a_e2, We3, a_e3, prep,
                                  dst0, E, indeg, batch, n, G, goff);
  k_scan_local<<<SB, 256, 0, stream>>>(indeg, row_off, bsum, n, 1);
  k_scan_tops<<<1, 64, 0, stream>>>(bsum, boff, SB);
  k_scan_add<<<SB, 256, 0, stream>>>(row_off, boff, n);
  k_scatter<<<(Ef + TB - 1) / TB, TB, 0, stream>>>(src0, dst0, E, n, row_off, cursor, csr_src, csr_eid);
  k_loopattr<<<(n + 3) / 4, 256, 0, stream>>>(n, row_off, csr_eid, edge_attr, lattr);
  k_eterm_csr<<<(Ef + n + TB - 1) / TB, TB, 0, stream>>>(csr_eid, edge_attr, lattr, prep, x,
                                                         et1c, et2c, et3c, sterm, dterm, xp, E, Ef, n);

  // ---- Layer 1 (H=4), rank-7 factorized ----
  k_agg4_l1<<<(n + 3) / 4, 256, 0, stream>>>(xp, sterm, dterm, et1c, row_off, csr_src,
                                             W1, b1, Af16, n);

  // ---- Layer 2 (H=4) ----
  k_gemm_mfma<4, 4><<<n / 64, 256, 0, stream>>>(Af16, Wt2, gbf, sterm, dterm, a_s2, a_d2);
  k_agg4<<<(n + 3) / 4, 256, 0, stream>>>(gbf, sterm, dterm, et2c, row_off, csr_src, b2, Af16, n);

  // ---- Layer 3 (H=1) ----
  k_gemm_mfma<1, 1><<<n / 64, 256, 0, stream>>>(Af16, Wt3, gbf, sterm, dterm, a_s3, a_d3);
  k_agg1<<<(n + 3) / 4, 256, 0, stream>>>(gbf, sterm, dterm, et3c, row_off, csr_src, b3, bufB, n);

  // ---- readout + MLP ----  d_out layout: [out(G)] [readout(G*64)]
  float* out_scalar = (float*)d_out;
  float* out_ro = out_scalar + G;
  k_readout_mlp<<<G, 256, 0, stream>>>(bufB, goff, p1w, p1b, p2w, p2b, p3w, p3b, out_ro, out_scalar);
}